// Round 6
// baseline (339.599 us; speedup 1.0000x reference)
//
#include <hip/hip_runtime.h>
#include <math.h>

constexpr int B = 128, N = 512, HID = 512, NH = 8, DH = 64;

// ---------------------------------------------------------------------------
// K1: query = w_seed_w*seed + w_seed_b; q = w_q @ query;
//     qk[h][j] = (1/sqrt(DH)) * sum_d q[h*64+d] * w_v[(h*64+d)*HID + j]
// grid 64 (h = bid>>3, jc = bid&7), block 64
// ---------------------------------------------------------------------------
__global__ __launch_bounds__(64) void k1_qk(
    const float* __restrict__ w_q, const float* __restrict__ w_v,
    const float* __restrict__ w_sw, const float* __restrict__ w_sb,
    const float* __restrict__ seed, float* __restrict__ qk)
{
    __shared__ __align__(16) float query_s[HID];
    __shared__ float q_s[DH];
    const int t  = threadIdx.x;
    const int h  = blockIdx.x >> 3;
    const int jc = blockIdx.x & 7;
    const float sv = seed[0];
    #pragma unroll
    for (int k = 0; k < 8; ++k) {
        const int j = t * 8 + k;
        query_s[j] = w_sw[j] * sv + w_sb[j];
    }
    __syncthreads();
    {
        const float* row = w_q + (size_t)(h * DH + t) * HID;
        float acc = 0.f;
        for (int j = 0; j < HID; j += 4) {
            const float4 wv = *(const float4*)(row + j);
            acc += wv.x * query_s[j]     + wv.y * query_s[j + 1]
                 + wv.z * query_s[j + 2] + wv.w * query_s[j + 3];
        }
        q_s[t] = acc;
    }
    __syncthreads();
    {
        const int j = jc * 64 + t;
        float acc = 0.f;
        for (int d = 0; d < DH; ++d)
            acc += q_s[d] * w_v[(size_t)(h * DH + d) * HID + j];
        qk[h * HID + j] = acc * 0.125f;   // fold 1/sqrt(64)
    }
}

// ---------------------------------------------------------------------------
// Dual-row head-folding butterfly: two independent 6-deep shuffle chains
// interleaved for ILP. Reduces va[8],vb[8] (8 head-partials each) to one
// scalar per lane-group; lane l<8 ends with head hh_out(l).
// ---------------------------------------------------------------------------
__device__ __forceinline__ void fold2(float va[NH], float vb[NH], int l,
                                      float& ra, float& rb)
{
    #pragma unroll
    for (int i = 0; i < 4; ++i) {
        const float a0 = __shfl_xor(va[i], 1, 64), a1 = __shfl_xor(va[i + 4], 1, 64);
        const float b0 = __shfl_xor(vb[i], 1, 64), b1 = __shfl_xor(vb[i + 4], 1, 64);
        va[i] = (l & 1) ? (va[i + 4] + a1) : (va[i] + a0);
        vb[i] = (l & 1) ? (vb[i + 4] + b1) : (vb[i] + b0);
    }
    #pragma unroll
    for (int i = 0; i < 2; ++i) {
        const float a0 = __shfl_xor(va[i], 2, 64), a1 = __shfl_xor(va[i + 2], 2, 64);
        const float b0 = __shfl_xor(vb[i], 2, 64), b1 = __shfl_xor(vb[i + 2], 2, 64);
        va[i] = (l & 2) ? (va[i + 2] + a1) : (va[i] + a0);
        vb[i] = (l & 2) ? (vb[i + 2] + b1) : (vb[i] + b0);
    }
    {
        const float a0 = __shfl_xor(va[0], 4, 64), a1 = __shfl_xor(va[1], 4, 64);
        const float b0 = __shfl_xor(vb[0], 4, 64), b1 = __shfl_xor(vb[1], 4, 64);
        va[0] = (l & 4) ? (va[1] + a1) : (va[0] + a0);
        vb[0] = (l & 4) ? (vb[1] + b1) : (vb[0] + b0);
    }
    va[0] += __shfl_xor(va[0], 8, 64);  vb[0] += __shfl_xor(vb[0], 8, 64);
    va[0] += __shfl_xor(va[0], 16, 64); vb[0] += __shfl_xor(vb[0], 16, 64);
    va[0] += __shfl_xor(va[0], 32, 64); vb[0] += __shfl_xor(vb[0], 32, 64);
    ra = va[0]; rb = vb[0];
}

// ---------------------------------------------------------------------------
// KE: e[b][hh][n] = <h[b,n,:], qk[hh,:]> — wave-per-row, coalesced (1KB/instr),
// 2 rows in flight per iteration. ALSO zeroes ctx[b][c*512..] for KC's atomics.
// grid B*8 (b = bid>>3, 64-row chunk c = bid&7), block 256 (4 waves).
// ---------------------------------------------------------------------------
__global__ __launch_bounds__(256) void ke_logits(
    const float* __restrict__ hbuf, const int* __restrict__ lengths,
    const float* __restrict__ qk, float* __restrict__ e_ws,
    float* __restrict__ ctx)
{
    const int t = threadIdx.x;
    const int l = t & 63;
    const int w = t >> 6;
    const int b = blockIdx.x >> 3;
    const int c = blockIdx.x & 7;
    const int n0 = c * 64;
    const int len = lengths[b];

    // zero this block's ctx slice (ordering: KE completes before KC dispatch)
    {
        float* cz = ctx + (size_t)b * (NH * HID) + c * 512;
        cz[t] = 0.f;
        cz[t + 256] = 0.f;
    }
    if (n0 >= len) return;                    // block-uniform exit

    float4 qlo[NH], qhi[NH];
    #pragma unroll
    for (int hh = 0; hh < NH; ++hh) {
        qlo[hh] = *(const float4*)&qk[hh * HID + l * 4];
        qhi[hh] = *(const float4*)&qk[hh * HID + 256 + l * 4];
    }

    const int nmax = min(n0 + 64, len);
    const float* hb = hbuf + (size_t)b * N * HID;
    const int hh_out = ((l & 1) << 2) | (l & 2) | ((l >> 2) & 1);

    for (int k = 0; k < 8; ++k) {
        const int na = n0 + w + 8 * k;
        if (na >= nmax) break;                // wave-uniform within stride group
        const int nb = min(na + 4, nmax - 1);

        const float* rowa = hb + (size_t)na * HID;
        const float* rowb = hb + (size_t)nb * HID;
        const float4 a0 = *(const float4*)(rowa + l * 4);
        const float4 a1 = *(const float4*)(rowa + 256 + l * 4);
        const float4 b0 = *(const float4*)(rowb + l * 4);
        const float4 b1 = *(const float4*)(rowb + 256 + l * 4);

        float va[NH], vb[NH];
        #pragma unroll
        for (int hh = 0; hh < NH; ++hh) {
            va[hh] = a0.x * qlo[hh].x + a0.y * qlo[hh].y
                   + a0.z * qlo[hh].z + a0.w * qlo[hh].w
                   + a1.x * qhi[hh].x + a1.y * qhi[hh].y
                   + a1.z * qhi[hh].z + a1.w * qhi[hh].w;
            vb[hh] = b0.x * qlo[hh].x + b0.y * qlo[hh].y
                   + b0.z * qlo[hh].z + b0.w * qlo[hh].w
                   + b1.x * qhi[hh].x + b1.y * qhi[hh].y
                   + b1.z * qhi[hh].z + b1.w * qhi[hh].w;
        }
        float ra, rb;
        fold2(va, vb, l, ra, rb);
        if (l < 8) {
            e_ws[(size_t)(b * NH + hh_out) * N + na] = ra;
            if (na + 4 < nmax)
                e_ws[(size_t)(b * NH + hh_out) * N + nb] = rb;
        }
    }
}

// ---------------------------------------------------------------------------
// KS: masked softmax per (b,hh); writes alpha (head-major, zeros past len)
// and interleaved al_t[b][n][hh]. grid B*2, block 256 (wave w -> head grp*4+w).
// ---------------------------------------------------------------------------
__global__ __launch_bounds__(256) void ks_softmax(
    const float* __restrict__ e_ws, const int* __restrict__ lengths,
    float* __restrict__ alpha, float* __restrict__ al_t)
{
    const int b    = blockIdx.x >> 1;
    const int grp  = blockIdx.x & 1;
    const int lane = threadIdx.x & 63;
    const int hh   = grp * 4 + (threadIdx.x >> 6);
    const int len  = lengths[b];

    const float* e = e_ws + (size_t)(b * NH + hh) * N;
    float ev[8];
    float m = -3.0e38f;
    #pragma unroll
    for (int it = 0; it < 8; ++it) {
        const int n = it * 64 + lane;
        ev[it] = (n < len) ? e[n] : -3.0e38f;
        m = fmaxf(m, ev[it]);
    }
    #pragma unroll
    for (int off = 32; off; off >>= 1)
        m = fmaxf(m, __shfl_xor(m, off, 64));
    float s = 0.f;
    #pragma unroll
    for (int it = 0; it < 8; ++it) {
        ev[it] = __expf(ev[it] - m);
        s += ev[it];
    }
    #pragma unroll
    for (int off = 32; off; off >>= 1)
        s += __shfl_xor(s, off, 64);
    const float inv = 1.f / s;
    float* ao = alpha + (size_t)(b * NH + hh) * N;
    float* at = al_t + (size_t)b * N * NH + hh;
    #pragma unroll
    for (int it = 0; it < 8; ++it) {
        const int n   = it * 64 + lane;
        const float v = (n < len) ? ev[it] * inv : 0.f;
        ao[n]      = v;
        at[n * NH] = v;
    }
}

// ---------------------------------------------------------------------------
// KC: ctx[b][hh][j] += sum over 64-row chunk of alpha*h — atomics into ctx
// (pre-zeroed by KE). grid B*8, block 256 (g = t>>7 row parity, cq = t&127).
// g-groups combined in LDS; g==0 threads issue 32 atomicAdds each.
// ---------------------------------------------------------------------------
__global__ __launch_bounds__(256) void kc_ctx(
    const float* __restrict__ hbuf, const int* __restrict__ lengths,
    const float* __restrict__ al_t, float* __restrict__ ctx)
{
    __shared__ __align__(16) float4 red[NH][128];   // 16 KB
    const int t   = threadIdx.x;
    const int b   = blockIdx.x >> 3;
    const int c   = blockIdx.x & 7;
    const int n0  = c * 64;
    const int g   = t >> 7;               // wave-uniform
    const int cq  = t & 127;
    const int len = lengths[b];
    const int nend = min(len - n0, 64);
    if (nend <= 0) return;                // block-uniform exit

    float4 acc[NH];
    #pragma unroll
    for (int hh = 0; hh < NH; ++hh) { acc[hh].x = acc[hh].y = acc[hh].z = acc[hh].w = 0.f; }

    const float* hb = hbuf + ((size_t)b * N + n0) * HID + cq * 4;
    const float* ap = al_t + ((size_t)b * N + n0) * NH;   // block-uniform
    #pragma unroll 4
    for (int ln = g; ln < nend; ln += 2) {
        const float4 hv = *(const float4*)(hb + (size_t)ln * HID);
        const float* a = ap + ln * NH;                    // uniform -> s_load
        acc[0].x += a[0] * hv.x; acc[0].y += a[0] * hv.y; acc[0].z += a[0] * hv.z; acc[0].w += a[0] * hv.w;
        acc[1].x += a[1] * hv.x; acc[1].y += a[1] * hv.y; acc[1].z += a[1] * hv.z; acc[1].w += a[1] * hv.w;
        acc[2].x += a[2] * hv.x; acc[2].y += a[2] * hv.y; acc[2].z += a[2] * hv.z; acc[2].w += a[2] * hv.w;
        acc[3].x += a[3] * hv.x; acc[3].y += a[3] * hv.y; acc[3].z += a[3] * hv.z; acc[3].w += a[3] * hv.w;
        acc[4].x += a[4] * hv.x; acc[4].y += a[4] * hv.y; acc[4].z += a[4] * hv.z; acc[4].w += a[4] * hv.w;
        acc[5].x += a[5] * hv.x; acc[5].y += a[5] * hv.y; acc[5].z += a[5] * hv.z; acc[5].w += a[5] * hv.w;
        acc[6].x += a[6] * hv.x; acc[6].y += a[6] * hv.y; acc[6].z += a[6] * hv.z; acc[6].w += a[6] * hv.w;
        acc[7].x += a[7] * hv.x; acc[7].y += a[7] * hv.y; acc[7].z += a[7] * hv.z; acc[7].w += a[7] * hv.w;
    }
    if (g == 1) {
        #pragma unroll
        for (int hh = 0; hh < NH; ++hh) red[hh][cq] = acc[hh];
    }
    __syncthreads();
    if (g == 0) {
        #pragma unroll
        for (int hh = 0; hh < NH; ++hh) {
            const float4 r = red[hh][cq];
            float* dst = ctx + (size_t)b * (NH * HID) + hh * HID + cq * 4;
            atomicAdd(dst + 0, acc[hh].x + r.x);
            atomicAdd(dst + 1, acc[hh].y + r.y);
            atomicAdd(dst + 2, acc[hh].z + r.z);
            atomicAdd(dst + 3, acc[hh].w + r.w);
        }
    }
}

// ---------------------------------------------------------------------------
// KD1: oh[b][p] = <ctx[b][p>>6][:], w_v[p][:]>   (p in [0,512))
// grid 64 (head ht = bid&7, b-tile bt = bid>>3 of 16), block 256
// thread: d = t&63 (p = ht*64+d), bs = t>>6; 4 b's per thread.
// ---------------------------------------------------------------------------
__global__ __launch_bounds__(256) void kd1_oh(
    const float* __restrict__ ctx, const float* __restrict__ w_v,
    float* __restrict__ oh)
{
    const int t  = threadIdx.x;
    const int ht = blockIdx.x & 7;
    const int bt = blockIdx.x >> 3;
    const int d  = t & 63;
    const int bs = t >> 6;
    const int p  = ht * 64 + d;
    const float* wrow = w_v + (size_t)p * HID;

    float acc[4] = {0.f, 0.f, 0.f, 0.f};
    for (int j = 0; j < HID; j += 4) {
        const float4 wv = *(const float4*)(wrow + j);
        #pragma unroll
        for (int bi = 0; bi < 4; ++bi) {
            const int bb = bt * 16 + bs * 4 + bi;
            const float4 cv = *(const float4*)&ctx[(size_t)bb * (NH * HID) + ht * HID + j];
            acc[bi] += wv.x * cv.x + wv.y * cv.y + wv.z * cv.z + wv.w * cv.w;
        }
    }
    #pragma unroll
    for (int bi = 0; bi < 4; ++bi) {
        const int bb = bt * 16 + bs * 4 + bi;
        oh[(size_t)bb * HID + p] = acc[bi];
    }
}

// ---------------------------------------------------------------------------
// KD2: out[b][i] = <oh[b][:], w_o[i][:]>
// grid 64 (i-tile it = bid&7, b-tile bt = bid>>3 of 16), block 256
// ---------------------------------------------------------------------------
__global__ __launch_bounds__(256) void kd2_out(
    const float* __restrict__ oh, const float* __restrict__ w_o,
    float* __restrict__ out)
{
    const int t  = threadIdx.x;
    const int it = blockIdx.x & 7;
    const int bt = blockIdx.x >> 3;
    const int d  = t & 63;
    const int bs = t >> 6;
    const int i  = it * 64 + d;
    const float* wrow = w_o + (size_t)i * HID;

    float acc[4] = {0.f, 0.f, 0.f, 0.f};
    for (int j = 0; j < HID; j += 4) {
        const float4 wv = *(const float4*)(wrow + j);
        #pragma unroll
        for (int bi = 0; bi < 4; ++bi) {
            const int bb = bt * 16 + bs * 4 + bi;
            const float4 ov = *(const float4*)&oh[(size_t)bb * HID + j];
            acc[bi] += wv.x * ov.x + wv.y * ov.y + wv.z * ov.z + wv.w * ov.w;
        }
    }
    #pragma unroll
    for (int bi = 0; bi < 4; ++bi) {
        const int bb = bt * 16 + bs * 4 + bi;
        out[(size_t)bb * HID + i] = acc[bi];
    }
}

// ---------------------------------------------------------------------------
extern "C" void kernel_launch(void* const* d_in, const int* in_sizes, int n_in,
                              void* d_out, int out_size, void* d_ws, size_t ws_size,
                              hipStream_t stream) {
    const float* h     = (const float*)d_in[0];
    const int*   lens  = (const int*)  d_in[1];
    const float* w_q   = (const float*)d_in[2];
    // d_in[3] = w_k: dead compute in the reference, intentionally unused
    const float* w_v   = (const float*)d_in[4];
    const float* w_o   = (const float*)d_in[5];
    const float* w_sw  = (const float*)d_in[6];
    const float* w_sb  = (const float*)d_in[7];
    const float* seed  = (const float*)d_in[8];

    float* out   = (float*)d_out;            // [B, HID]
    float* alpha = out + (size_t)B * HID;    // [B, NH, N, 1]

    // ws (floats): qk[4096] | e[524288] | al_t[524288] | ctx[524288] | oh[65536]
    float* ws   = (float*)d_ws;
    float* qk   = ws;
    float* e_ws = qk + NH * HID;
    float* al_t = e_ws + (size_t)B * NH * N;
    float* ctx  = al_t + (size_t)B * N * NH;
    float* oh   = ctx + (size_t)B * NH * HID;

    hipLaunchKernelGGL(k1_qk,      dim3(64),    dim3(64),  0, stream,
                       w_q, w_v, w_sw, w_sb, seed, qk);
    hipLaunchKernelGGL(ke_logits,  dim3(B * 8), dim3(256), 0, stream,
                       h, lens, qk, e_ws, ctx);
    hipLaunchKernelGGL(ks_softmax, dim3(B * 2), dim3(256), 0, stream,
                       e_ws, lens, alpha, al_t);
    hipLaunchKernelGGL(kc_ctx,     dim3(B * 8), dim3(256), 0, stream,
                       h, lens, al_t, ctx);
    hipLaunchKernelGGL(kd1_oh,     dim3(64),    dim3(256), 0, stream,
                       ctx, w_v, oh);
    hipLaunchKernelGGL(kd2_out,    dim3(64),    dim3(256), 0, stream,
                       oh, w_o, out);
}

// Round 7
// 291.042 us; speedup vs baseline: 1.1668x; 1.1668x over previous
//
#include <hip/hip_runtime.h>
#include <math.h>

constexpr int B = 128, N = 512, HID = 512, NH = 8, DH = 64;

// ---------------------------------------------------------------------------
// K1: query = w_seed_w*seed + w_seed_b; q = w_q @ query;
//     qk[h][j] = (1/sqrt(DH)) * sum_d q[h*64+d] * w_v[(h*64+d)*HID + j]
// grid 64 (h = bid>>3, jc = bid&7), block 64
// ---------------------------------------------------------------------------
__global__ __launch_bounds__(64) void k1_qk(
    const float* __restrict__ w_q, const float* __restrict__ w_v,
    const float* __restrict__ w_sw, const float* __restrict__ w_sb,
    const float* __restrict__ seed, float* __restrict__ qk)
{
    __shared__ __align__(16) float query_s[HID];
    __shared__ float q_s[DH];
    const int t  = threadIdx.x;
    const int h  = blockIdx.x >> 3;
    const int jc = blockIdx.x & 7;
    const float sv = seed[0];
    #pragma unroll
    for (int k = 0; k < 8; ++k) {
        const int j = t * 8 + k;
        query_s[j] = w_sw[j] * sv + w_sb[j];
    }
    __syncthreads();
    {
        const float* row = w_q + (size_t)(h * DH + t) * HID;
        float acc = 0.f;
        for (int j = 0; j < HID; j += 4) {
            const float4 wv = *(const float4*)(row + j);
            acc += wv.x * query_s[j]     + wv.y * query_s[j + 1]
                 + wv.z * query_s[j + 2] + wv.w * query_s[j + 3];
        }
        q_s[t] = acc;
    }
    __syncthreads();
    {
        const int j = jc * 64 + t;
        float acc = 0.f;
        for (int d = 0; d < DH; ++d)
            acc += q_s[d] * w_v[(size_t)(h * DH + d) * HID + j];
        qk[h * HID + j] = acc * 0.125f;   // fold 1/sqrt(64)
    }
}

// ---------------------------------------------------------------------------
// KE: e[b][hh][n] = <h[b,n,:], qk[hh,:]>   — wave-per-row, fully coalesced
// (identical to R5's proven version).
// grid B*8 (b = bid>>3, 64-row chunk c = bid&7), block 256 (4 waves).
// ---------------------------------------------------------------------------
__global__ __launch_bounds__(256) void ke_logits(
    const float* __restrict__ hbuf, const int* __restrict__ lengths,
    const float* __restrict__ qk, float* __restrict__ e_ws)
{
    const int t = threadIdx.x;
    const int l = t & 63;
    const int w = t >> 6;
    const int b = blockIdx.x >> 3;
    const int c = blockIdx.x & 7;
    const int n0 = c * 64;
    const int len = lengths[b];
    if (n0 >= len) return;                    // block-uniform exit

    float4 qlo[NH], qhi[NH];
    #pragma unroll
    for (int hh = 0; hh < NH; ++hh) {
        qlo[hh] = *(const float4*)&qk[hh * HID + l * 4];
        qhi[hh] = *(const float4*)&qk[hh * HID + 256 + l * 4];
    }

    const int nmax = min(n0 + 64, len);
    const float* hb = hbuf + (size_t)b * N * HID;
    const int hh_out = ((l & 1) << 2) | (l & 2) | ((l >> 2) & 1);

    for (int n = n0 + w; n < nmax; n += 4) {
        const float* row = hb + (size_t)n * HID;
        const float4 h0 = *(const float4*)(row + l * 4);        // 1KB/wave
        const float4 h1 = *(const float4*)(row + 256 + l * 4);  // 1KB/wave
        float v[NH];
        #pragma unroll
        for (int hh = 0; hh < NH; ++hh)
            v[hh] = h0.x * qlo[hh].x + h0.y * qlo[hh].y
                  + h0.z * qlo[hh].z + h0.w * qlo[hh].w
                  + h1.x * qhi[hh].x + h1.y * qhi[hh].y
                  + h1.z * qhi[hh].z + h1.w * qhi[hh].w;

        #pragma unroll
        for (int i = 0; i < 4; ++i) {
            const float ax = __shfl_xor(v[i], 1, 64);
            const float bx = __shfl_xor(v[i + 4], 1, 64);
            v[i] = (l & 1) ? (v[i + 4] + bx) : (v[i] + ax);
        }
        #pragma unroll
        for (int i = 0; i < 2; ++i) {
            const float ax = __shfl_xor(v[i], 2, 64);
            const float bx = __shfl_xor(v[i + 2], 2, 64);
            v[i] = (l & 2) ? (v[i + 2] + bx) : (v[i] + ax);
        }
        {
            const float ax = __shfl_xor(v[0], 4, 64);
            const float bx = __shfl_xor(v[1], 4, 64);
            v[0] = (l & 4) ? (v[1] + bx) : (v[0] + ax);
        }
        v[0] += __shfl_xor(v[0], 8, 64);
        v[0] += __shfl_xor(v[0], 16, 64);
        v[0] += __shfl_xor(v[0], 32, 64);

        if (l < 8)
            e_ws[(size_t)(b * NH + hh_out) * N + n] = v[0];
    }
}

// ---------------------------------------------------------------------------
// KS: masked softmax per (b,hh); writes alpha (head-major, zeros past len)
// and interleaved al_t[b][n][hh]. grid B*2, block 256 (wave w -> head grp*4+w).
// ---------------------------------------------------------------------------
__global__ __launch_bounds__(256) void ks_softmax(
    const float* __restrict__ e_ws, const int* __restrict__ lengths,
    float* __restrict__ alpha, float* __restrict__ al_t)
{
    const int b    = blockIdx.x >> 1;
    const int grp  = blockIdx.x & 1;
    const int lane = threadIdx.x & 63;
    const int hh   = grp * 4 + (threadIdx.x >> 6);
    const int len  = lengths[b];

    const float* e = e_ws + (size_t)(b * NH + hh) * N;
    float ev[8];
    float m = -3.0e38f;
    #pragma unroll
    for (int it = 0; it < 8; ++it) {
        const int n = it * 64 + lane;
        ev[it] = (n < len) ? e[n] : -3.0e38f;
        m = fmaxf(m, ev[it]);
    }
    #pragma unroll
    for (int off = 32; off; off >>= 1)
        m = fmaxf(m, __shfl_xor(m, off, 64));
    float s = 0.f;
    #pragma unroll
    for (int it = 0; it < 8; ++it) {
        ev[it] = __expf(ev[it] - m);
        s += ev[it];
    }
    #pragma unroll
    for (int off = 32; off; off >>= 1)
        s += __shfl_xor(s, off, 64);
    const float inv = 1.f / s;
    float* ao = alpha + (size_t)(b * NH + hh) * N;
    float* at = al_t + (size_t)b * N * NH + hh;
    #pragma unroll
    for (int it = 0; it < 8; ++it) {
        const int n   = it * 64 + lane;
        const float v = (n < len) ? ev[it] * inv : 0.f;
        ao[n]      = v;
        at[n * NH] = v;
    }
}

// ---------------------------------------------------------------------------
// KC: partial ctx over a 64-row chunk; the two row-parity groups (g = t>>7)
// are combined in LDS (NO atomics), so only 8 partials per b are stored.
// grid B*8, block 256. Out-of-range chunks store zeros (consumer sums all 8).
// ctxp layout: [b][chunk 0..7][hh][HID]
// ---------------------------------------------------------------------------
__global__ __launch_bounds__(256) void kc_ctx(
    const float* __restrict__ hbuf, const int* __restrict__ lengths,
    const float* __restrict__ al_t, float* __restrict__ ctxp)
{
    __shared__ __align__(16) float4 red[NH][128];   // 16 KB
    const int t   = threadIdx.x;
    const int b   = blockIdx.x >> 3;
    const int c   = blockIdx.x & 7;
    const int n0  = c * 64;
    const int g   = t >> 7;               // wave-uniform
    const int cq  = t & 127;
    const int len = lengths[b];
    const int nend = min(len - n0, 64);

    float4 acc[NH];
    #pragma unroll
    for (int hh = 0; hh < NH; ++hh) { acc[hh].x = acc[hh].y = acc[hh].z = acc[hh].w = 0.f; }

    const float* hb = hbuf + ((size_t)b * N + n0) * HID + cq * 4;
    const float* ap = al_t + ((size_t)b * N + n0) * NH;   // block-uniform
    #pragma unroll 4
    for (int ln = g; ln < nend; ln += 2) {
        const float4 hv = *(const float4*)(hb + (size_t)ln * HID);
        const float* a = ap + ln * NH;                    // uniform -> s_load
        acc[0].x += a[0] * hv.x; acc[0].y += a[0] * hv.y; acc[0].z += a[0] * hv.z; acc[0].w += a[0] * hv.w;
        acc[1].x += a[1] * hv.x; acc[1].y += a[1] * hv.y; acc[1].z += a[1] * hv.z; acc[1].w += a[1] * hv.w;
        acc[2].x += a[2] * hv.x; acc[2].y += a[2] * hv.y; acc[2].z += a[2] * hv.z; acc[2].w += a[2] * hv.w;
        acc[3].x += a[3] * hv.x; acc[3].y += a[3] * hv.y; acc[3].z += a[3] * hv.z; acc[3].w += a[3] * hv.w;
        acc[4].x += a[4] * hv.x; acc[4].y += a[4] * hv.y; acc[4].z += a[4] * hv.z; acc[4].w += a[4] * hv.w;
        acc[5].x += a[5] * hv.x; acc[5].y += a[5] * hv.y; acc[5].z += a[5] * hv.z; acc[5].w += a[5] * hv.w;
        acc[6].x += a[6] * hv.x; acc[6].y += a[6] * hv.y; acc[6].z += a[6] * hv.z; acc[6].w += a[6] * hv.w;
        acc[7].x += a[7] * hv.x; acc[7].y += a[7] * hv.y; acc[7].z += a[7] * hv.z; acc[7].w += a[7] * hv.w;
    }
    if (g == 1) {
        #pragma unroll
        for (int hh = 0; hh < NH; ++hh) red[hh][cq] = acc[hh];
    }
    __syncthreads();
    if (g == 0) {
        float* cp = ctxp + (size_t)((b * 8 + c) * NH) * HID + cq * 4;
        #pragma unroll
        for (int hh = 0; hh < NH; ++hh) {
            const float4 r = red[hh][cq];
            float4 o;
            o.x = acc[hh].x + r.x; o.y = acc[hh].y + r.y;
            o.z = acc[hh].z + r.z; o.w = acc[hh].w + r.w;
            *(float4*)(cp + (size_t)hh * HID) = o;
        }
    }
}

// ---------------------------------------------------------------------------
// KD1: oh[b][p] = <sum_c ctxp[b][c][p>>6][:], w_v[p][:]>
// grid 64 (ht = bid&7, b-tile bt = bid>>3 of 8 -> 16 b's each), block 256.
// Phase A: cooperative coalesced sum of 8 partials into LDS (16 b x 512).
// Phase B: thread (d,bs) dots w_v row p=ht*64+d against broadcast LDS rows.
// ---------------------------------------------------------------------------
__global__ __launch_bounds__(256) void kd1_oh(
    const float* __restrict__ ctxp, const float* __restrict__ w_v,
    float* __restrict__ oh)
{
    __shared__ __align__(16) float ctx_s[16][HID];   // 32 KB
    const int t  = threadIdx.x;
    const int ht = blockIdx.x & 7;
    const int bt = blockIdx.x >> 3;

    // Phase A: 16 b x 128 j4 work items; sum 8 chunk-partials each.
    for (int idx = t; idx < 16 * 128; idx += 256) {
        const int bb_l = idx >> 7;          // 0..15
        const int j4   = idx & 127;
        const int bb   = bt * 16 + bb_l;
        const float* p0 = ctxp + ((size_t)(bb * 8) * NH + ht) * HID + j4 * 4;
        float4 s = {0.f, 0.f, 0.f, 0.f};
        #pragma unroll
        for (int cc = 0; cc < 8; ++cc) {
            const float4 v = *(const float4*)(p0 + (size_t)cc * NH * HID);
            s.x += v.x; s.y += v.y; s.z += v.z; s.w += v.w;
        }
        *(float4*)&ctx_s[bb_l][j4 * 4] = s;
    }
    __syncthreads();

    // Phase B
    const int d  = t & 63;
    const int bs = t >> 6;
    const int p  = ht * 64 + d;
    const float* wrow = w_v + (size_t)p * HID;
    float acc[4] = {0.f, 0.f, 0.f, 0.f};
    for (int j = 0; j < HID; j += 4) {
        const float4 wv = *(const float4*)(wrow + j);
        #pragma unroll
        for (int bi = 0; bi < 4; ++bi) {
            const float4 cv = *(const float4*)&ctx_s[bs * 4 + bi][j];  // broadcast
            acc[bi] += wv.x * cv.x + wv.y * cv.y + wv.z * cv.z + wv.w * cv.w;
        }
    }
    #pragma unroll
    for (int bi = 0; bi < 4; ++bi) {
        const int bb = bt * 16 + bs * 4 + bi;
        oh[(size_t)bb * HID + p] = acc[bi];
    }
}

// ---------------------------------------------------------------------------
// KD2: out[b][i] = <oh[b][:], w_o[i][:]>
// grid 64 (it = bid&7, bt = bid>>3), block 256. Same LDS-stage structure.
// ---------------------------------------------------------------------------
__global__ __launch_bounds__(256) void kd2_out(
    const float* __restrict__ oh, const float* __restrict__ w_o,
    float* __restrict__ out)
{
    __shared__ __align__(16) float oh_s[16][HID];    // 32 KB
    const int t  = threadIdx.x;
    const int it = blockIdx.x & 7;
    const int bt = blockIdx.x >> 3;

    for (int idx = t; idx < 16 * 128; idx += 256) {
        const int bb_l = idx >> 7;
        const int j4   = idx & 127;
        const int bb   = bt * 16 + bb_l;
        *(float4*)&oh_s[bb_l][j4 * 4] =
            *(const float4*)&oh[(size_t)bb * HID + j4 * 4];
    }
    __syncthreads();

    const int d  = t & 63;
    const int bs = t >> 6;
    const int i  = it * 64 + d;
    const float* wrow = w_o + (size_t)i * HID;
    float acc[4] = {0.f, 0.f, 0.f, 0.f};
    for (int j = 0; j < HID; j += 4) {
        const float4 wv = *(const float4*)(wrow + j);
        #pragma unroll
        for (int bi = 0; bi < 4; ++bi) {
            const float4 ov = *(const float4*)&oh_s[bs * 4 + bi][j];   // broadcast
            acc[bi] += wv.x * ov.x + wv.y * ov.y + wv.z * ov.z + wv.w * ov.w;
        }
    }
    #pragma unroll
    for (int bi = 0; bi < 4; ++bi) {
        const int bb = bt * 16 + bs * 4 + bi;
        out[(size_t)bb * HID + i] = acc[bi];
    }
}

// ---------------------------------------------------------------------------
extern "C" void kernel_launch(void* const* d_in, const int* in_sizes, int n_in,
                              void* d_out, int out_size, void* d_ws, size_t ws_size,
                              hipStream_t stream) {
    const float* h     = (const float*)d_in[0];
    const int*   lens  = (const int*)  d_in[1];
    const float* w_q   = (const float*)d_in[2];
    // d_in[3] = w_k: dead compute in the reference, intentionally unused
    const float* w_v   = (const float*)d_in[4];
    const float* w_o   = (const float*)d_in[5];
    const float* w_sw  = (const float*)d_in[6];
    const float* w_sb  = (const float*)d_in[7];
    const float* seed  = (const float*)d_in[8];

    float* out   = (float*)d_out;            // [B, HID]
    float* alpha = out + (size_t)B * HID;    // [B, NH, N, 1]

    // ws (floats): qk[4096] | e[524288] | al_t[524288] | ctxp[B*8*NH*HID] | oh[65536]
    float* ws   = (float*)d_ws;
    float* qk   = ws;
    float* e_ws = qk + NH * HID;
    float* al_t = e_ws + (size_t)B * NH * N;
    float* ctxp = al_t + (size_t)B * N * NH;
    float* oh   = ctxp + (size_t)B * 8 * NH * HID;

    hipLaunchKernelGGL(k1_qk,      dim3(64),    dim3(64),  0, stream,
                       w_q, w_v, w_sw, w_sb, seed, qk);
    hipLaunchKernelGGL(ke_logits,  dim3(B * 8), dim3(256), 0, stream,
                       h, lens, qk, e_ws);
    hipLaunchKernelGGL(ks_softmax, dim3(B * 2), dim3(256), 0, stream,
                       e_ws, lens, alpha, al_t);
    hipLaunchKernelGGL(kc_ctx,     dim3(B * 8), dim3(256), 0, stream,
                       h, lens, al_t, ctxp);
    hipLaunchKernelGGL(kd1_oh,     dim3(64),    dim3(256), 0, stream,
                       ctxp, w_v, oh);
    hipLaunchKernelGGL(kd2_out,    dim3(64),    dim3(256), 0, stream,
                       oh, w_o, out);
}

// Round 8
// 280.646 us; speedup vs baseline: 1.2101x; 1.0370x over previous
//
#include <hip/hip_runtime.h>
#include <math.h>

constexpr int B = 128, N = 512, HID = 512, NH = 8, DH = 64;

// ---------------------------------------------------------------------------
// K1: query = w_seed_w*seed + w_seed_b; q = w_q @ query;
//     qk[h][j] = (1/sqrt(DH)) * sum_d q[h*64+d] * w_v[(h*64+d)*HID + j]
// grid 64 (h = bid>>3, jc = bid&7), block 64
// ---------------------------------------------------------------------------
__global__ __launch_bounds__(64) void k1_qk(
    const float* __restrict__ w_q, const float* __restrict__ w_v,
    const float* __restrict__ w_sw, const float* __restrict__ w_sb,
    const float* __restrict__ seed, float* __restrict__ qk)
{
    __shared__ __align__(16) float query_s[HID];
    __shared__ float q_s[DH];
    const int t  = threadIdx.x;
    const int h  = blockIdx.x >> 3;
    const int jc = blockIdx.x & 7;
    const float sv = seed[0];
    #pragma unroll
    for (int k = 0; k < 8; ++k) {
        const int j = t * 8 + k;
        query_s[j] = w_sw[j] * sv + w_sb[j];
    }
    __syncthreads();
    {
        const float* row = w_q + (size_t)(h * DH + t) * HID;
        float acc = 0.f;
        for (int j = 0; j < HID; j += 4) {
            const float4 wv = *(const float4*)(row + j);
            acc += wv.x * query_s[j]     + wv.y * query_s[j + 1]
                 + wv.z * query_s[j + 2] + wv.w * query_s[j + 3];
        }
        q_s[t] = acc;
    }
    __syncthreads();
    {
        const int j = jc * 64 + t;
        float acc = 0.f;
        for (int d = 0; d < DH; ++d)
            acc += q_s[d] * w_v[(size_t)(h * DH + d) * HID + j];
        qk[h * HID + j] = acc * 0.125f;   // fold 1/sqrt(64)
    }
}

// ---------------------------------------------------------------------------
// KE: e_t[b][n][hh] = <h[b,n,:], qk[hh,:]> — wave-per-row, coalesced loads
// (R5/R7-proven); store now CONTIGUOUS (32B per row from lanes 0..7).
// grid B*8 (b = bid>>3, 64-row chunk c = bid&7), block 256 (4 waves).
// Rows n >= len are never written (consumer masks by len).
// ---------------------------------------------------------------------------
__global__ __launch_bounds__(256) void ke_logits(
    const float* __restrict__ hbuf, const int* __restrict__ lengths,
    const float* __restrict__ qk, float* __restrict__ e_t)
{
    const int t = threadIdx.x;
    const int l = t & 63;
    const int w = t >> 6;
    const int b = blockIdx.x >> 3;
    const int c = blockIdx.x & 7;
    const int n0 = c * 64;
    const int len = lengths[b];
    if (n0 >= len) return;                    // block-uniform exit

    float4 qlo[NH], qhi[NH];
    #pragma unroll
    for (int hh = 0; hh < NH; ++hh) {
        qlo[hh] = *(const float4*)&qk[hh * HID + l * 4];
        qhi[hh] = *(const float4*)&qk[hh * HID + 256 + l * 4];
    }

    const int nmax = min(n0 + 64, len);
    const float* hb = hbuf + (size_t)b * N * HID;
    const int hh_out = ((l & 1) << 2) | (l & 2) | ((l >> 2) & 1);

    for (int n = n0 + w; n < nmax; n += 4) {
        const float* row = hb + (size_t)n * HID;
        const float4 h0 = *(const float4*)(row + l * 4);        // 1KB/wave
        const float4 h1 = *(const float4*)(row + 256 + l * 4);  // 1KB/wave
        float v[NH];
        #pragma unroll
        for (int hh = 0; hh < NH; ++hh)
            v[hh] = h0.x * qlo[hh].x + h0.y * qlo[hh].y
                  + h0.z * qlo[hh].z + h0.w * qlo[hh].w
                  + h1.x * qhi[hh].x + h1.y * qhi[hh].y
                  + h1.z * qhi[hh].z + h1.w * qhi[hh].w;

        #pragma unroll
        for (int i = 0; i < 4; ++i) {
            const float ax = __shfl_xor(v[i], 1, 64);
            const float bx = __shfl_xor(v[i + 4], 1, 64);
            v[i] = (l & 1) ? (v[i + 4] + bx) : (v[i] + ax);
        }
        #pragma unroll
        for (int i = 0; i < 2; ++i) {
            const float ax = __shfl_xor(v[i], 2, 64);
            const float bx = __shfl_xor(v[i + 2], 2, 64);
            v[i] = (l & 2) ? (v[i + 2] + bx) : (v[i] + ax);
        }
        {
            const float ax = __shfl_xor(v[0], 4, 64);
            const float bx = __shfl_xor(v[1], 4, 64);
            v[0] = (l & 4) ? (v[1] + bx) : (v[0] + ax);
        }
        v[0] += __shfl_xor(v[0], 8, 64);
        v[0] += __shfl_xor(v[0], 16, 64);
        v[0] += __shfl_xor(v[0], 32, 64);

        if (l < 8)
            e_t[((size_t)b * N + n) * NH + hh_out] = v[0];   // 32B contiguous
    }
}

// ---------------------------------------------------------------------------
// KCS: fused softmax + ctx partial. grid B*8 (b = bid>>3, chunk c = bid&7),
// block 256.
//   ph0: per-head max over all n (each thread owns rows 2t,2t+1 from e_t)
//   ph1: per-head expsum (same register data)
//   ph2: alpha for THIS chunk -> global (coalesced) + LDS stash
//   ph3: MAC over chunk rows (R7 KC structure: g-parity split, LDS combine)
// Redundancy: softmax stats recomputed by all 8 blocks of b (16KB L2-hot
// reads + ~4k exp each) — cheap vs a separate kernel + al_t round-trip.
// ---------------------------------------------------------------------------
__global__ __launch_bounds__(256) void kcs_ctx(
    const float* __restrict__ hbuf, const int* __restrict__ lengths,
    const float* __restrict__ e_t, float* __restrict__ alpha,
    float* __restrict__ ctxp)
{
    __shared__ float red_s[NH][256];                 // 8 KB (max, then sum)
    __shared__ float stat_s[2][NH];                  // m, 1/s
    __shared__ __align__(16) float al_s[64][8];      // 2 KB (32B rows, aligned)
    __shared__ __align__(16) float4 red4[NH][128];   // 16 KB
    const int t = threadIdx.x;
    const int l = t & 63;
    const int w = t >> 6;
    const int b = blockIdx.x >> 3;
    const int c = blockIdx.x & 7;
    const int n0 = c * 64;
    const int len = lengths[b];

    // ---- ph0: load e rows 2t, 2t+1 (64B coalesced); per-head valid max ----
    const float* eb = e_t + (size_t)b * N * NH;
    float4 ev[4];
    {
        const float4* ep = (const float4*)(eb + t * 16);
        ev[0] = ep[0]; ev[1] = ep[1]; ev[2] = ep[2]; ev[3] = ep[3];
    }
    const bool va = (2 * t) < len, vb = (2 * t + 1) < len;
    const float* e0 = (const float*)&ev[0];          // row 2t,   heads 0..7
    const float* e1 = (const float*)&ev[2];          // row 2t+1, heads 0..7
    #pragma unroll
    for (int hh = 0; hh < NH; ++hh) {
        float m = -3.0e38f;
        if (va) m = e0[hh];
        if (vb) m = fmaxf(m, e1[hh]);
        red_s[hh][t] = m;
    }
    __syncthreads();
    #pragma unroll
    for (int k = 0; k < 2; ++k) {                    // wave w -> heads w, w+4
        const int hh = w + k * 4;
        float v = fmaxf(fmaxf(red_s[hh][l], red_s[hh][l + 64]),
                        fmaxf(red_s[hh][l + 128], red_s[hh][l + 192]));
        #pragma unroll
        for (int off = 32; off; off >>= 1)
            v = fmaxf(v, __shfl_xor(v, off, 64));
        if (l == 0) stat_s[0][hh] = v;
    }
    __syncthreads();

    // ---- ph1: per-head expsum ----
    #pragma unroll
    for (int hh = 0; hh < NH; ++hh) {
        const float m = stat_s[0][hh];
        float s = 0.f;
        if (va) s += __expf(e0[hh] - m);
        if (vb) s += __expf(e1[hh] - m);
        red_s[hh][t] = s;                            // safe: barrier above
    }
    __syncthreads();
    #pragma unroll
    for (int k = 0; k < 2; ++k) {
        const int hh = w + k * 4;
        float v = red_s[hh][l] + red_s[hh][l + 64]
                + red_s[hh][l + 128] + red_s[hh][l + 192];
        #pragma unroll
        for (int off = 32; off; off >>= 1)
            v += __shfl_xor(v, off, 64);
        if (l == 0) stat_s[1][hh] = 1.f / v;
    }
    __syncthreads();

    // ---- ph2: alpha for this chunk: global write (coalesced) + LDS stash ----
    #pragma unroll
    for (int k = 0; k < 2; ++k) {
        const int idx = t + k * 256;                 // 0..511
        const int hh = idx >> 6;
        const int nl = idx & 63;
        const int n  = n0 + nl;
        float v = 0.f;
        if (n < len)
            v = __expf(eb[(size_t)n * NH + hh] - stat_s[0][hh]) * stat_s[1][hh];
        alpha[(size_t)(b * NH + hh) * N + n] = v;
        al_s[nl][hh] = v;
    }
    __syncthreads();

    // ---- ph3: MAC over chunk rows; alpha from LDS broadcast ----
    const int g  = t >> 7;               // wave-uniform row parity
    const int cq = t & 127;
    const int nend = min(len - n0, 64);

    float4 acc[NH];
    #pragma unroll
    for (int hh = 0; hh < NH; ++hh) { acc[hh].x = acc[hh].y = acc[hh].z = acc[hh].w = 0.f; }

    const float* hb = hbuf + ((size_t)b * N + n0) * HID + cq * 4;
    #pragma unroll 4
    for (int ln = g; ln < nend; ln += 2) {
        const float4 hv = *(const float4*)(hb + (size_t)ln * HID);
        const float4 a0 = *(const float4*)&al_s[ln][0];   // same addr: broadcast
        const float4 a1 = *(const float4*)&al_s[ln][4];
        acc[0].x += a0.x * hv.x; acc[0].y += a0.x * hv.y; acc[0].z += a0.x * hv.z; acc[0].w += a0.x * hv.w;
        acc[1].x += a0.y * hv.x; acc[1].y += a0.y * hv.y; acc[1].z += a0.y * hv.z; acc[1].w += a0.y * hv.w;
        acc[2].x += a0.z * hv.x; acc[2].y += a0.z * hv.y; acc[2].z += a0.z * hv.z; acc[2].w += a0.z * hv.w;
        acc[3].x += a0.w * hv.x; acc[3].y += a0.w * hv.y; acc[3].z += a0.w * hv.z; acc[3].w += a0.w * hv.w;
        acc[4].x += a1.x * hv.x; acc[4].y += a1.x * hv.y; acc[4].z += a1.x * hv.z; acc[4].w += a1.x * hv.w;
        acc[5].x += a1.y * hv.x; acc[5].y += a1.y * hv.y; acc[5].z += a1.y * hv.z; acc[5].w += a1.y * hv.w;
        acc[6].x += a1.z * hv.x; acc[6].y += a1.z * hv.y; acc[6].z += a1.z * hv.z; acc[6].w += a1.z * hv.w;
        acc[7].x += a1.w * hv.x; acc[7].y += a1.w * hv.y; acc[7].z += a1.w * hv.z; acc[7].w += a1.w * hv.w;
    }
    if (g == 1) {
        #pragma unroll
        for (int hh = 0; hh < NH; ++hh) red4[hh][cq] = acc[hh];
    }
    __syncthreads();
    if (g == 0) {
        float* cp = ctxp + (size_t)((b * 8 + c) * NH) * HID + cq * 4;
        #pragma unroll
        for (int hh = 0; hh < NH; ++hh) {
            const float4 r = red4[hh][cq];
            float4 o;
            o.x = acc[hh].x + r.x; o.y = acc[hh].y + r.y;
            o.z = acc[hh].z + r.z; o.w = acc[hh].w + r.w;
            *(float4*)(cp + (size_t)hh * HID) = o;
        }
    }
}

// ---------------------------------------------------------------------------
// KD1: oh[b][p] = <sum_c ctxp[b][c][p>>6][:], w_v[p][:]>
// grid 64 (ht = bid&7, b-tile bt = bid>>3), block 256.
// ---------------------------------------------------------------------------
__global__ __launch_bounds__(256) void kd1_oh(
    const float* __restrict__ ctxp, const float* __restrict__ w_v,
    float* __restrict__ oh)
{
    __shared__ __align__(16) float ctx_s[16][HID];   // 32 KB
    const int t  = threadIdx.x;
    const int ht = blockIdx.x & 7;
    const int bt = blockIdx.x >> 3;

    for (int idx = t; idx < 16 * 128; idx += 256) {
        const int bb_l = idx >> 7;
        const int j4   = idx & 127;
        const int bb   = bt * 16 + bb_l;
        const float* p0 = ctxp + ((size_t)(bb * 8) * NH + ht) * HID + j4 * 4;
        float4 s = {0.f, 0.f, 0.f, 0.f};
        #pragma unroll
        for (int cc = 0; cc < 8; ++cc) {
            const float4 v = *(const float4*)(p0 + (size_t)cc * NH * HID);
            s.x += v.x; s.y += v.y; s.z += v.z; s.w += v.w;
        }
        *(float4*)&ctx_s[bb_l][j4 * 4] = s;
    }
    __syncthreads();

    const int d  = t & 63;
    const int bs = t >> 6;
    const int p  = ht * 64 + d;
    const float* wrow = w_v + (size_t)p * HID;
    float acc[4] = {0.f, 0.f, 0.f, 0.f};
    for (int j = 0; j < HID; j += 4) {
        const float4 wv = *(const float4*)(wrow + j);
        #pragma unroll
        for (int bi = 0; bi < 4; ++bi) {
            const float4 cv = *(const float4*)&ctx_s[bs * 4 + bi][j];  // broadcast
            acc[bi] += wv.x * cv.x + wv.y * cv.y + wv.z * cv.z + wv.w * cv.w;
        }
    }
    #pragma unroll
    for (int bi = 0; bi < 4; ++bi) {
        const int bb = bt * 16 + bs * 4 + bi;
        oh[(size_t)bb * HID + p] = acc[bi];
    }
}

// ---------------------------------------------------------------------------
// KD2: out[b][i] = <oh[b][:], w_o[i][:]>
// grid 64 (it = bid&7, bt = bid>>3), block 256.
// ---------------------------------------------------------------------------
__global__ __launch_bounds__(256) void kd2_out(
    const float* __restrict__ oh, const float* __restrict__ w_o,
    float* __restrict__ out)
{
    __shared__ __align__(16) float oh_s[16][HID];    // 32 KB
    const int t  = threadIdx.x;
    const int it = blockIdx.x & 7;
    const int bt = blockIdx.x >> 3;

    for (int idx = t; idx < 16 * 128; idx += 256) {
        const int bb_l = idx >> 7;
        const int j4   = idx & 127;
        const int bb   = bt * 16 + bb_l;
        *(float4*)&oh_s[bb_l][j4 * 4] =
            *(const float4*)&oh[(size_t)bb * HID + j4 * 4];
    }
    __syncthreads();

    const int d  = t & 63;
    const int bs = t >> 6;
    const int i  = it * 64 + d;
    const float* wrow = w_o + (size_t)i * HID;
    float acc[4] = {0.f, 0.f, 0.f, 0.f};
    for (int j = 0; j < HID; j += 4) {
        const float4 wv = *(const float4*)(wrow + j);
        #pragma unroll
        for (int bi = 0; bi < 4; ++bi) {
            const float4 ov = *(const float4*)&oh_s[bs * 4 + bi][j];   // broadcast
            acc[bi] += wv.x * ov.x + wv.y * ov.y + wv.z * ov.z + wv.w * ov.w;
        }
    }
    #pragma unroll
    for (int bi = 0; bi < 4; ++bi) {
        const int bb = bt * 16 + bs * 4 + bi;
        out[(size_t)bb * HID + i] = acc[bi];
    }
}

// ---------------------------------------------------------------------------
extern "C" void kernel_launch(void* const* d_in, const int* in_sizes, int n_in,
                              void* d_out, int out_size, void* d_ws, size_t ws_size,
                              hipStream_t stream) {
    const float* h     = (const float*)d_in[0];
    const int*   lens  = (const int*)  d_in[1];
    const float* w_q   = (const float*)d_in[2];
    // d_in[3] = w_k: dead compute in the reference, intentionally unused
    const float* w_v   = (const float*)d_in[4];
    const float* w_o   = (const float*)d_in[5];
    const float* w_sw  = (const float*)d_in[6];
    const float* w_sb  = (const float*)d_in[7];
    const float* seed  = (const float*)d_in[8];

    float* out   = (float*)d_out;            // [B, HID]
    float* alpha = out + (size_t)B * HID;    // [B, NH, N, 1]

    // ws (floats): qk[4096] | e_t[B*N*NH] | ctxp[B*8*NH*HID] | oh[65536]
    float* ws   = (float*)d_ws;
    float* qk   = ws;
    float* e_t  = qk + NH * HID;
    float* ctxp = e_t + (size_t)B * N * NH;
    float* oh   = ctxp + (size_t)B * 8 * NH * HID;

    hipLaunchKernelGGL(k1_qk,     dim3(64),    dim3(64),  0, stream,
                       w_q, w_v, w_sw, w_sb, seed, qk);
    hipLaunchKernelGGL(ke_logits, dim3(B * 8), dim3(256), 0, stream,
                       h, lens, qk, e_t);
    hipLaunchKernelGGL(kcs_ctx,   dim3(B * 8), dim3(256), 0, stream,
                       h, lens, e_t, alpha, ctxp);
    hipLaunchKernelGGL(kd1_oh,    dim3(64),    dim3(256), 0, stream,
                       ctxp, w_v, oh);
    hipLaunchKernelGGL(kd2_out,   dim3(64),    dim3(256), 0, stream,
                       oh, w_o, out);
}